// Round 2
// baseline (505.418 us; speedup 1.0000x reference)
//
#include <hip/hip_runtime.h>
#include <math.h>

// MoLoRARouter: logits = x[16384,4096] @ gate_w[64,4096]^T (fp32) -> softmax
// -> top-2 -> renorm.  fp32 emulated as split-2 fp16 MFMA:
//   v = h + l/2048,  h = fp16(v), l = fp16((v-h)*2048)   (~22-24 mantissa bits)
//   logit = hh + (hl+lh)/2048 + ll/2048^2  -> error ~1e-6, fp32-reorder class.
//
// V2 (latency-bound fix): no LDS staging, no main-loop barriers.
//  - gate_w pre-converted once to split-fp16 (wh/wl) in workspace by wconv_kernel;
//    B-fragments load directly as half8 from L2 (w = 1 MB, L2-resident).
//  - x A-fragments load directly global->VGPR (16 rows x 128B per fragment set,
//    coalesced), converted in-register. Depth-2 prefetch hides HBM latency.
//  - K-split 2: each wave does 16 tokens x 64 experts x K=2048.
//    2048 waves total -> 2 waves/SIMD (vs 1 before). Partials combined via one
//    10 KB LDS exchange + single __syncthreads.
//  - top-2 fully in-register: 16-lane __shfl_xor butterfly merge, strict-> /
//    lower-index-wins tie-break (matches verified sequential scan).

typedef _Float16 half8 __attribute__((ext_vector_type(8)));
typedef _Float16 half4 __attribute__((ext_vector_type(4)));
typedef float floatx4 __attribute__((ext_vector_type(4)));

constexpr int Hdim  = 4096;
constexpr int Edim  = 64;
constexpr int NTOK  = 16384;
constexpr int KHALF = 2048;          // K range per wave (K-split 2)
constexpr int NKT2  = KHALF / 64;    // 32 K-chunks of 64 floats per wave
constexpr float SCL  = 2048.0f;
constexpr float ISCL = 1.0f / 2048.0f;

// ---- pre-kernel: gate_w fp32 -> split fp16 (wh, wl), row-major [64][4096] ----
__global__ __launch_bounds__(256)
void wconv_kernel(const float* __restrict__ gw,
                  _Float16* __restrict__ wh,
                  _Float16* __restrict__ wl)
{
    const int idx = blockIdx.x * 256 + threadIdx.x;      // 65536 threads x 4 floats
    const float4 v = ((const float4*)gw)[idx];
    const float* p = (const float*)&v;
    half4 h, l;
    #pragma unroll
    for (int c = 0; c < 4; ++c) {
        const _Float16 hh = (_Float16)p[c];
        h[c] = hh;
        l[c] = (_Float16)((p[c] - (float)hh) * SCL);
    }
    *(half4*)(wh + 4 * idx) = h;
    *(half4*)(wl + 4 * idx) = l;
}

// ---- main kernel ----
__global__ __launch_bounds__(256, 2)
void router_kernel(const float* __restrict__ x,
                   const _Float16* __restrict__ wh,
                   const _Float16* __restrict__ wl,
                   float* __restrict__ out)
{
    __shared__ float sp[2][64][20];    // K-half partial exchange (stride 20: bank spread)

    const int tid   = threadIdx.x;
    const int wv    = tid >> 6;
    const int lane  = tid & 63;
    const int ln15  = lane & 15;
    const int quad  = lane >> 4;
    const int grp   = wv >> 1;         // token group within block (2 per block)
    const int khalf = wv & 1;          // K-half this wave owns
    const int t0    = (blockIdx.x * 2 + grp) * 16;
    const int koff  = khalf * KHALF;

    // per-lane fragment bases (A row = lane&15, k = (lane>>4)*8 + j  — verified map)
    const float*    xa  = x  + (size_t)(t0 + ln15) * Hdim + koff + quad * 8;
    const _Float16* whp = wh + (size_t)ln15 * Hdim + koff + quad * 8;
    const _Float16* wlp = wl + (size_t)ln15 * Hdim + koff + quad * 8;

    floatx4 accm[4], accc[4], accl[4];
    #pragma unroll
    for (int nt = 0; nt < 4; ++nt) {
        accm[nt] = (floatx4)0.0f;
        accc[nt] = (floatx4)0.0f;
        accl[nt] = (floatx4)0.0f;
    }

    float4 A0[4], A1[4];               // x raw, depth-2 rotation (static names)
    half8 bAh[4], bAl[4];              // B for kk=0 (prefetched one body ahead)
    half8 bBh[4], bBl[4];              // B for kk=1

    // ---- prologue: A0<-x[0], A1<-x[1], bA<-B[0][kk0], bB<-B[0][kk1] ----
    #pragma unroll
    for (int j = 0; j < 4; ++j) {
        A0[j] = *(const float4*)(xa + 0 * 64 + (j >> 1) * 32 + (j & 1) * 4);
        A1[j] = *(const float4*)(xa + 1 * 64 + (j >> 1) * 32 + (j & 1) * 4);
    }
    #pragma unroll
    for (int nt = 0; nt < 4; ++nt) {
        bAh[nt] = *(const half8*)(whp + nt * 16 * Hdim);
        bAl[nt] = *(const half8*)(wlp + nt * 16 * Hdim);
        bBh[nt] = *(const half8*)(whp + nt * 16 * Hdim + 32);
        bBl[nt] = *(const half8*)(wlp + nt * 16 * Hdim + 32);
    }

    // split-convert 8 floats (two float4) -> half8 h + half8 l
    auto cvt8 = [&](const float4& a, const float4& b, half8& h, half8& l) {
        const float* pa = (const float*)&a;
        const float* pb = (const float*)&b;
        #pragma unroll
        for (int c = 0; c < 4; ++c) {
            _Float16 hh = (_Float16)pa[c];
            h[c] = hh;
            l[c] = (_Float16)((pa[c] - (float)hh) * SCL);
            hh = (_Float16)pb[c];
            h[c + 4] = hh;
            l[c + 4] = (_Float16)((pb[c] - (float)hh) * SCL);
        }
    };

    auto body = [&](float4 (&Acur)[4], int kt) {
        const int ktn = (kt + 1 < NKT2) ? kt + 1 : 0;   // clamped B prefetch
        const int ka  = (kt + 2 < NKT2) ? kt + 2 : 0;   // clamped A prefetch
        half8 ah, al;

        // kk = 0: compute with bA
        cvt8(Acur[0], Acur[1], ah, al);
        #pragma unroll
        for (int nt = 0; nt < 4; ++nt) {
            accm[nt] = __builtin_amdgcn_mfma_f32_16x16x32_f16(ah, bAh[nt], accm[nt], 0, 0, 0);
            accc[nt] = __builtin_amdgcn_mfma_f32_16x16x32_f16(ah, bAl[nt], accc[nt], 0, 0, 0);
            accc[nt] = __builtin_amdgcn_mfma_f32_16x16x32_f16(al, bAh[nt], accc[nt], 0, 0, 0);
            accl[nt] = __builtin_amdgcn_mfma_f32_16x16x32_f16(al, bAl[nt], accl[nt], 0, 0, 0);
        }
        // refill bA for next body's kk0 (one full body of distance to use)
        #pragma unroll
        for (int nt = 0; nt < 4; ++nt) {
            bAh[nt] = *(const half8*)(whp + nt * 16 * Hdim + ktn * 64);
            bAl[nt] = *(const half8*)(wlp + nt * 16 * Hdim + ktn * 64);
        }

        // kk = 1: compute with bB
        cvt8(Acur[2], Acur[3], ah, al);
        #pragma unroll
        for (int nt = 0; nt < 4; ++nt) {
            accm[nt] = __builtin_amdgcn_mfma_f32_16x16x32_f16(ah, bBh[nt], accm[nt], 0, 0, 0);
            accc[nt] = __builtin_amdgcn_mfma_f32_16x16x32_f16(ah, bBl[nt], accc[nt], 0, 0, 0);
            accc[nt] = __builtin_amdgcn_mfma_f32_16x16x32_f16(al, bBh[nt], accc[nt], 0, 0, 0);
            accl[nt] = __builtin_amdgcn_mfma_f32_16x16x32_f16(al, bBl[nt], accl[nt], 0, 0, 0);
        }
        // refill bB for next body's kk1
        #pragma unroll
        for (int nt = 0; nt < 4; ++nt) {
            bBh[nt] = *(const half8*)(whp + nt * 16 * Hdim + ktn * 64 + 32);
            bBl[nt] = *(const half8*)(wlp + nt * 16 * Hdim + ktn * 64 + 32);
        }

        // A depth-2 prefetch into the buffer just consumed (used at kt+2)
        #pragma unroll
        for (int j = 0; j < 4; ++j)
            Acur[j] = *(const float4*)(xa + ka * 64 + (j >> 1) * 32 + (j & 1) * 4);
    };

    for (int kt = 0; kt < NKT2; kt += 2) {
        body(A0, kt);
        body(A1, kt + 1);
    }

    // ---- combine split terms; merge K-halves through LDS (single barrier) ----
    floatx4 v[4];
    #pragma unroll
    for (int nt = 0; nt < 4; ++nt)
        v[nt] = accm[nt] + accc[nt] * ISCL + accl[nt] * (ISCL * ISCL);

    if (khalf) {
        #pragma unroll
        for (int nt = 0; nt < 4; ++nt)
            *(floatx4*)&sp[grp][lane][4 * nt] = v[nt];
    }
    __syncthreads();

    if (!khalf) {
        #pragma unroll
        for (int nt = 0; nt < 4; ++nt)
            v[nt] += *(const floatx4*)&sp[grp][lane][4 * nt];

        // D layout: token = quad*4 + i, expert = nt*16 + ln15.
        // Top-2 per token: local over nt (ascending e), then 16-lane xor butterfly.
        #pragma unroll
        for (int i = 0; i < 4; ++i) {
            float m1 = -INFINITY, m2 = -INFINITY;
            int i1 = 0, i2 = 0;
            #pragma unroll
            for (int nt = 0; nt < 4; ++nt) {
                const float val = v[nt][i];
                const int e = nt * 16 + ln15;
                if (val > m1)      { m2 = m1; i2 = i1; m1 = val; i1 = e; }
                else if (val > m2) { m2 = val; i2 = e; }
            }
            #pragma unroll
            for (int mk = 1; mk <= 8; mk <<= 1) {
                const float om1 = __shfl_xor(m1, mk);
                const int   oi1 = __shfl_xor(i1, mk);
                const float om2 = __shfl_xor(m2, mk);
                const int   oi2 = __shfl_xor(i2, mk);
                // merge two sorted top-2 sets; ties -> lower expert index
                const bool aw = (m1 > om1) || (m1 == om1 && i1 < oi1);
                const float w1v = aw ? m1 : om1;  const int w1i = aw ? i1 : oi1;
                const float ca  = aw ? m2 : om2;  const int cai = aw ? i2 : oi2; // winner's 2nd
                const float cb  = aw ? om1 : m1;  const int cbi = aw ? oi1 : i1; // loser's 1st
                const bool sw = (ca > cb) || (ca == cb && cai < cbi);
                m1 = w1v; i1 = w1i;
                m2 = sw ? ca : cb;
                i2 = sw ? cai : cbi;
            }
            if (ln15 == 0) {
                const float r   = expf(m2 - m1);
                const float inv = 1.0f / (1.0f + r);
                const int t = t0 + quad * 4 + i;
                float* ow = out + 2 * (size_t)t;
                ow[0] = inv;
                ow[1] = r * inv;
                float* oi = out + 2 * (size_t)NTOK + 2 * (size_t)t;
                oi[0] = (float)i1;
                oi[1] = (float)i2;
            }
        }
    }
}

extern "C" void kernel_launch(void* const* d_in, const int* in_sizes, int n_in,
                              void* d_out, int out_size, void* d_ws, size_t ws_size,
                              hipStream_t stream) {
    const float* x  = (const float*)d_in[0];   // [4,4096,4096] fp32
    const float* gw = (const float*)d_in[1];   // [64,4096] fp32
    float* out = (float*)d_out;                // weights(32768) ++ indices(32768)
    _Float16* wh = (_Float16*)d_ws;            // [64][4096] split-high
    _Float16* wl = wh + (size_t)Edim * Hdim;   // [64][4096] split-low (1 MB total)

    hipLaunchKernelGGL(wconv_kernel, dim3(256), dim3(256), 0, stream, gw, wh, wl);
    hipLaunchKernelGGL(router_kernel, dim3(NTOK / 32), dim3(256), 0, stream,
                       x, wh, wl, out);
}